// Round 16
// baseline (229.035 us; speedup 1.0000x reference)
//
#include <hip/hip_runtime.h>

#define NNODES 100000
#define NEDGES 1600000
#define HID 16
#define MSG 16
#define NTYPE 16
#define NCLS 64

#define BSH 7
#define NBK ((NNODES + 127) >> 7)           // 782 buckets of 128 nodes (dst>>7)
#define CHSZ 8192
#define NCH ((NEDGES + CHSZ - 1) / CHSZ)    // 196 edge chunks
#define BCAP 2304                           // fixed bucket capacity (mean 2046 + 5.7 sigma)
#define BLKPB 5                             // 4 full 512-blocks + 256 tail
#define AGG_BLOCKS (NBK * BLKPB)            // 3910

// At2 layout: [ty][i][h], row stride 20 floats (proven conflict-light for b128)
#define ASTR 20
#define ATY  320

#define MAGG_N (NNODES * MSG)               // 1.6M floats

__device__ __forceinline__ float sigmoid_f(float x) {
    return 1.0f / (1.0f + __expf(-x));
}
__device__ __forceinline__ float tanh_f(float x) {
    x = fminf(fmaxf(x, -15.0f), 15.0f);
    float e = __expf(2.0f * x);
    return (e - 1.0f) / (e + 1.0f);
}

// ---------------------------------------------------------------------------
// Phase A (single pass): zero magg slice, per-chunk LDS bucket count ->
// global atomic segment reservation in gcnt -> clustered write into
// fixed-capacity bucket regions. rec = src | et<<17 | (dst&127)<<21
// ---------------------------------------------------------------------------
__global__ __launch_bounds__(1024) void scat_k(const int* __restrict__ src,
                                               const int* __restrict__ dst,
                                               const int* __restrict__ et,
                                               int* __restrict__ gcnt,
                                               int* __restrict__ rec,
                                               float* __restrict__ magg) {
    __shared__ int cnt[NBK];
    const int t = threadIdx.x, ch = blockIdx.x;

    // zero this block's slice of magg (stream-ordered before agg5 reads it)
    {
        const int per = (MAGG_N / 4 + NCH - 1) / NCH;   // float4 units per block
        float4* m4 = (float4*)magg;
        int s0 = ch * per;
        int s1 = s0 + per; if (s1 > MAGG_N / 4) s1 = MAGG_N / 4;
        const float4 z = {0.f, 0.f, 0.f, 0.f};
        for (int k = s0 + t; k < s1; k += 1024) m4[k] = z;
    }

    for (int k = t; k < NBK; k += 1024) cnt[k] = 0;
    __syncthreads();
    int dcache[CHSZ / 1024];
    #pragma unroll
    for (int k = 0; k < CHSZ / 1024; k++) {
        int e = ch * CHSZ + k * 1024 + t;
        dcache[k] = (e < NEDGES) ? dst[e] : -1;
        if (dcache[k] >= 0) atomicAdd(&cnt[dcache[k] >> BSH], 1);
    }
    __syncthreads();
    // reserve this block's sub-segment in each bucket; cnt[b] becomes cursor
    for (int k = t; k < NBK; k += 1024) {
        int c = cnt[k];
        cnt[k] = c ? atomicAdd(&gcnt[k], c) : 0;
    }
    __syncthreads();
    #pragma unroll
    for (int k = 0; k < CHSZ / 1024; k++) {
        int e = ch * CHSZ + k * 1024 + t;
        if (e < NEDGES) {
            int d = dcache[k];
            int b = d >> BSH;
            int pos = atomicAdd(&cnt[b], 1);
            rec[b * BCAP + pos] = src[e] | (et[e] << 17) | ((d & 127) << 21);
        }
    }
}

// ---------------------------------------------------------------------------
// Phase B: in-LDS counting sort of each bucket by TYPE (16 bins).
// Perf-only: type-pure 64-slot wave windows -> At2 ds_read_b128 broadcasts
// across the wave's 4 groups. agg5 is order-independent (LDS accumulator),
// so an unsorted/oversized bucket is still correct.
// ---------------------------------------------------------------------------
__global__ __launch_bounds__(512) void sortt_k(const int* __restrict__ gcnt,
                                               int* __restrict__ rec) {
    __shared__ int buf[BCAP];
    __shared__ int cnt16[NTYPE];
    __shared__ int base16[NTYPE];
    const int t = threadIdx.x, b = blockIdx.x;
    const int jb = b * BCAP;
    const int len = gcnt[b];
    if (len <= 0 || len > BCAP) return;

    if (t < NTYPE) cnt16[t] = 0;
    for (int k = t; k < len; k += 512) buf[k] = rec[jb + k];
    __syncthreads();
    for (int k = t; k < len; k += 512) atomicAdd(&cnt16[(buf[k] >> 17) & 15], 1);
    __syncthreads();
    if (t == 0) {
        int run = 0;
        #pragma unroll
        for (int q = 0; q < NTYPE; q++) { base16[q] = run; run += cnt16[q]; }
    }
    __syncthreads();
    for (int k = t; k < len; k += 512) {
        int r = buf[k];
        int p = atomicAdd(&base16[(r >> 17) & 15], 1);
        rec[jb + p] = r;
    }
}

// ---------------------------------------------------------------------------
// Phase C: aggregation with LDS accumulator. Block (b,br) covers slots
// [br*512, br*512+512) of bucket b; 16-lane group owns 16 slots.
// Type-sorted slots -> wave's A-reads broadcast. Paired pre-issued gathers
// (proven pipeline config: 512 thr, plain bounds). acc[128][17] LDS atomics,
// one clustered global-atomic flush per block.
// ---------------------------------------------------------------------------
__global__ __launch_bounds__(512) void agg5_k(const float* __restrict__ feat,
                                              const int* __restrict__ rec,
                                              const int* __restrict__ gcnt,
                                              const float* __restrict__ edge_emb,
                                              float* __restrict__ magg) {
    __shared__ float At2[NTYPE * ATY];   // 20.5 KB
    __shared__ float acc[128 * 17];      // 8.7 KB
    __shared__ int recs[512];            // 2 KB
    const int t = threadIdx.x;
    const int b  = blockIdx.x / BLKPB;
    const int br = blockIdx.x % BLKPB;
    const int cnt = gcnt[b];
    const int w0 = br << 9;
    if (w0 >= cnt) return;               // uniform: whole block idle (acc all-zero)

    #pragma unroll
    for (int idx = t; idx < NTYPE * MSG * HID; idx += 512) {
        int ty = idx >> 8, rem = idx & 255, ii = rem >> 4, h = rem & 15;
        At2[ty * ATY + ii * ASTR + h] = edge_emb[idx];
    }
    for (int k = t; k < 128 * 17; k += 512) acc[k] = 0.0f;
    {
        int ns = BCAP - w0; ns = ns > 512 ? 512 : ns;
        if (t < ns) recs[t] = rec[b * BCAP + w0 + t];
    }
    __syncthreads();

    const int g = t >> 4, i = t & 15;
    const int base = g << 4;
    int vr = cnt - (w0 + base);
    const int vcnt = vr < 0 ? 0 : (vr > 16 ? 16 : vr);   // no early return: flush below

    #pragma unroll 1
    for (int p = 0; p < 16; p += 2) {
        if (p >= vcnt) break;
        const bool has2 = (p + 1) < vcnt;
        int r1 = recs[base + p];
        int r2 = has2 ? recs[base + p + 1] : r1;
        const float4* f1 = (const float4*)(feat + (size_t)(r1 & 0x1FFFF) * HID);
        const float4* f2 = (const float4*)(feat + (size_t)(r2 & 0x1FFFF) * HID);
        float4 Fa0 = f1[0], Fa1 = f1[1], Fa2 = f1[2], Fa3 = f1[3];
        float4 Fb0 = f2[0], Fb1 = f2[1], Fb2 = f2[2], Fb3 = f2[3];
        __builtin_amdgcn_sched_barrier(0);   // keep both gathers issued above

        {
            const float4* pa = (const float4*)(At2 + ((r1 >> 17) & 15) * ATY + i * ASTR);
            float4 A0 = pa[0], A1 = pa[1], A2 = pa[2], A3 = pa[3];
            float m1;
            m1  = A0.x*Fa0.x + A0.y*Fa0.y + A0.z*Fa0.z + A0.w*Fa0.w;
            m1 += A1.x*Fa1.x + A1.y*Fa1.y + A1.z*Fa1.z + A1.w*Fa1.w;
            m1 += A2.x*Fa2.x + A2.y*Fa2.y + A2.z*Fa2.z + A2.w*Fa2.w;
            m1 += A3.x*Fa3.x + A3.y*Fa3.y + A3.z*Fa3.z + A3.w*Fa3.w;
            atomicAdd(&acc[(((unsigned)r1) >> 21) * 17 + i], m1);
        }
        if (has2) {
            const float4* pb = (const float4*)(At2 + ((r2 >> 17) & 15) * ATY + i * ASTR);
            float4 B0 = pb[0], B1 = pb[1], B2 = pb[2], B3 = pb[3];
            float m2;
            m2  = B0.x*Fb0.x + B0.y*Fb0.y + B0.z*Fb0.z + B0.w*Fb0.w;
            m2 += B1.x*Fb1.x + B1.y*Fb1.y + B1.z*Fb1.z + B1.w*Fb1.w;
            m2 += B2.x*Fb2.x + B2.y*Fb2.y + B2.z*Fb2.z + B2.w*Fb2.w;
            m2 += B3.x*Fb3.x + B3.y*Fb3.y + B3.z*Fb3.z + B3.w*Fb3.w;
            atomicAdd(&acc[(((unsigned)r2) >> 21) * 17 + i], m2);
        }
    }
    __syncthreads();

    // clustered flush: 128 nodes x 16 dims, coalesced global atomics
    const int nb = b << BSH;
    for (int k = t; k < 128 * 16; k += 512) {
        int ln = k >> 4, ii = k & 15;
        int n = nb + ln;
        float v = acc[ln * 17 + ii];
        if (n < NNODES && v != 0.0f) atomicAdd(&magg[(size_t)n * MSG + ii], v);
    }
}

// ---------------------------------------------------------------------------
// Fallback atomic edge kernel (only if ws too small)
// ---------------------------------------------------------------------------
__global__ __launch_bounds__(256) void ggnn_edge(
    const float* __restrict__ feat,
    const int* __restrict__ src,
    const int* __restrict__ dst,
    const int* __restrict__ etype,
    const float* __restrict__ edge_emb,
    float* __restrict__ magg)
{
    __shared__ float At[NTYPE * MSG * HID];
    for (int idx = threadIdx.x; idx < NTYPE * MSG * HID; idx += 256) {
        int ty = idx >> 8, rem = idx & 255, i = rem >> 4, hh = rem & 15;
        At[(ty << 8) | (hh << 4) | i] = edge_emb[idx];
    }
    __syncthreads();
    const long long total = (long long)NEDGES * MSG;
    for (long long w = (long long)blockIdx.x * 256 + threadIdx.x; w < total;
         w += (long long)gridDim.x * 256) {
        const int e = (int)(w >> 4);
        const int i = (int)(w & 15);
        const int s = src[e];
        const int d = dst[e];
        const int ty = etype[e];
        const float4* fp = (const float4*)(feat + (size_t)s * HID);
        const float4 f0 = fp[0], f1 = fp[1], f2 = fp[2], f3 = fp[3];
        const float* a = At + (ty << 8) + i;
        float m;
        m  = a[0*16]*f0.x + a[1*16]*f0.y + a[2*16]*f0.z + a[3*16]*f0.w;
        m += a[4*16]*f1.x + a[5*16]*f1.y + a[6*16]*f1.z + a[7*16]*f1.w;
        m += a[8*16]*f2.x + a[9*16]*f2.y + a[10*16]*f2.z + a[11*16]*f2.w;
        m += a[12*16]*f3.x + a[13*16]*f3.y + a[14*16]*f3.z + a[15*16]*f3.w;
        atomicAdd(magg + (size_t)d * MSG + i, m);
    }
}

// ---------------------------------------------------------------------------
// Node kernel: GRU -> hnew in LDS -> output head with float4 stores.
// ---------------------------------------------------------------------------
__global__ __launch_bounds__(256) void node_k(
    const float* __restrict__ feat,
    const float* __restrict__ magg,
    const float* __restrict__ W_ih,
    const float* __restrict__ W_hh,
    const float* __restrict__ b_ih,
    const float* __restrict__ b_hh,
    const float* __restrict__ W_out,
    const float* __restrict__ b_out,
    float* __restrict__ out)
{
    __shared__ float hn_s[256 * 20];
    const int t = threadIdx.x;
    const int n = blockIdx.x * 256 + t;
    if (n < NNODES) {
        float hv[HID], mv[MSG];
        const float4* hp = (const float4*)(feat + (size_t)n * HID);
        const float4* mp = (const float4*)(magg + (size_t)n * MSG);
        #pragma unroll
        for (int q = 0; q < 4; q++) {
            float4 a = hp[q];
            hv[4*q+0] = a.x; hv[4*q+1] = a.y; hv[4*q+2] = a.z; hv[4*q+3] = a.w;
            float4 c = mp[q];
            mv[4*q+0] = c.x; mv[4*q+1] = c.y; mv[4*q+2] = c.z; mv[4*q+3] = c.w;
        }
        #pragma unroll
        for (int i = 0; i < HID; i++) {
            float xr = b_ih[i], xz = b_ih[16 + i], xn = b_ih[32 + i];
            float hr = b_hh[i], hz = b_hh[16 + i], hn = b_hh[32 + i];
            #pragma unroll
            for (int j = 0; j < HID; j++) {
                xr += W_ih[(i)      * 16 + j] * mv[j];
                xz += W_ih[(16 + i) * 16 + j] * mv[j];
                xn += W_ih[(32 + i) * 16 + j] * mv[j];
                hr += W_hh[(i)      * 16 + j] * hv[j];
                hz += W_hh[(16 + i) * 16 + j] * hv[j];
                hn += W_hh[(32 + i) * 16 + j] * hv[j];
            }
            float r  = sigmoid_f(xr + hr);
            float z  = sigmoid_f(xz + hz);
            float nn = tanh_f(xn + r * hn);
            hn_s[t * 20 + i] = (1.0f - z) * nn + z * hv[i];
        }
    }
    __syncthreads();

    const int w = t >> 6, g = (t >> 4) & 3, li = t & 15;
    float4 w4[4][4];
    #pragma unroll
    for (int rr = 0; rr < 4; rr++)
        #pragma unroll
        for (int qq = 0; qq < 4; qq++)
            w4[rr][qq] = ((const float4*)W_out)[(4 * li + rr) * 4 + qq];
    const float4 bo4 = ((const float4*)b_out)[li];
    const int nb = blockIdx.x * 256;

    #pragma unroll
    for (int it = 0; it < 16; it++) {
        int ln = it * 16 + w * 4 + g;
        int n2 = nb + ln;
        if (n2 < NNODES) {
            const float4* hq = (const float4*)(hn_s + ln * 20);
            float4 h0 = hq[0], h1 = hq[1], h2 = hq[2], h3 = hq[3];
            float4 o;
            o.x = bo4.x + w4[0][0].x*h0.x + w4[0][0].y*h0.y + w4[0][0].z*h0.z + w4[0][0].w*h0.w
                        + w4[0][1].x*h1.x + w4[0][1].y*h1.y + w4[0][1].z*h1.z + w4[0][1].w*h1.w
                        + w4[0][2].x*h2.x + w4[0][2].y*h2.y + w4[0][2].z*h2.z + w4[0][2].w*h2.w
                        + w4[0][3].x*h3.x + w4[0][3].y*h3.y + w4[0][3].z*h3.z + w4[0][3].w*h3.w;
            o.y = bo4.y + w4[1][0].x*h0.x + w4[1][0].y*h0.y + w4[1][0].z*h0.z + w4[1][0].w*h0.w
                        + w4[1][1].x*h1.x + w4[1][1].y*h1.y + w4[1][1].z*h1.z + w4[1][1].w*h1.w
                        + w4[1][2].x*h2.x + w4[1][2].y*h2.y + w4[1][2].z*h2.z + w4[1][2].w*h2.w
                        + w4[1][3].x*h3.x + w4[1][3].y*h3.y + w4[1][3].z*h3.z + w4[1][3].w*h3.w;
            o.z = bo4.z + w4[2][0].x*h0.x + w4[2][0].y*h0.y + w4[2][0].z*h0.z + w4[2][0].w*h0.w
                        + w4[2][1].x*h1.x + w4[2][1].y*h1.y + w4[2][1].z*h1.z + w4[2][1].w*h1.w
                        + w4[2][2].x*h2.x + w4[2][2].y*h2.y + w4[2][2].z*h2.z + w4[2][2].w*h2.w
                        + w4[2][3].x*h3.x + w4[2][3].y*h3.y + w4[2][3].z*h3.z + w4[2][3].w*h3.w;
            o.w = bo4.w + w4[3][0].x*h0.x + w4[3][0].y*h0.y + w4[3][0].z*h0.z + w4[3][0].w*h0.w
                        + w4[3][1].x*h1.x + w4[3][1].y*h1.y + w4[3][1].z*h1.z + w4[3][1].w*h1.w
                        + w4[3][2].x*h2.x + w4[3][2].y*h2.y + w4[3][2].z*h2.z + w4[3][2].w*h2.w
                        + w4[3][3].x*h3.x + w4[3][3].y*h3.y + w4[3][3].z*h3.z + w4[3][3].w*h3.w;
            ((float4*)(out + (size_t)n2 * NCLS))[li] = o;
        }
    }
}

extern "C" void kernel_launch(void* const* d_in, const int* in_sizes, int n_in,
                              void* d_out, int out_size, void* d_ws, size_t ws_size,
                              hipStream_t stream) {
    const float* feat     = (const float*)d_in[0];
    const int*   src      = (const int*)d_in[1];
    const int*   dst      = (const int*)d_in[2];
    const int*   etype    = (const int*)d_in[3];
    const float* edge_emb = (const float*)d_in[4];
    const float* W_ih     = (const float*)d_in[5];
    const float* W_hh     = (const float*)d_in[6];
    const float* b_ih     = (const float*)d_in[7];
    const float* b_hh     = (const float*)d_in[8];
    const float* W_out    = (const float*)d_in[9];
    const float* b_out    = (const float*)d_in[10];
    float* out = (float*)d_out;

    // workspace layout (4-byte elements): ~13.6 MB (proven budget)
    float* magg = (float*)d_ws;                        // NNODES*16
    int*   gcnt = (int*)d_ws + (size_t)MAGG_N;         // 1024 (NBK used)
    int*   rec  = gcnt + 1024;                         // NBK*BCAP
    size_t need = ((size_t)MAGG_N + 1024 + (size_t)NBK * BCAP) * 4;

    if (ws_size >= need) {
        hipMemsetAsync(gcnt, 0, 1024 * sizeof(int), stream);   // tiny
        scat_k  <<<NCH, 1024, 0, stream>>>(src, dst, etype, gcnt, rec, magg);
        sortt_k <<<NBK, 512, 0, stream>>>(gcnt, rec);
        agg5_k  <<<AGG_BLOCKS, 512, 0, stream>>>(feat, rec, gcnt, edge_emb, magg);
    } else {
        hipMemsetAsync(magg, 0, (size_t)MAGG_N * sizeof(float), stream);
        ggnn_edge<<<2560, 256, 0, stream>>>(feat, src, dst, etype, edge_emb, magg);
    }
    node_k<<<(NNODES + 255) / 256, 256, 0, stream>>>(
        feat, magg, W_ih, W_hh, b_ih, b_hh, W_out, b_out, out);
}

// Round 17
// 134.238 us; speedup vs baseline: 1.7062x; 1.7062x over previous
//
#include <hip/hip_runtime.h>

#define NNODES 100000
#define NEDGES 1600000
#define HID 16
#define MSG 16
#define NTYPE 16
#define NCLS 64

#define BSH 7
#define NBK ((NNODES + 127) >> 7)           // 782 buckets of 128 nodes (dst>>7)
#define CHSZ 8192
#define NCH ((NEDGES + CHSZ - 1) / CHSZ)    // 196 edge chunks
#define BCAP 2304                           // fixed bucket capacity (mean 2046 + 5.7 sigma)
#define BLKPB 5                             // 4 full 512-blocks + 256 tail
#define AGG_BLOCKS (NBK * BLKPB)            // 3910

// At2 layout: [ty][i][h], row stride 20 floats (proven conflict-light for b128)
#define ASTR 20
#define ATY  320

#define MAGG_N (NNODES * MSG)               // 1.6M floats

__device__ __forceinline__ float sigmoid_f(float x) {
    return 1.0f / (1.0f + __expf(-x));
}
__device__ __forceinline__ float tanh_f(float x) {
    x = fminf(fmaxf(x, -15.0f), 15.0f);
    float e = __expf(2.0f * x);
    return (e - 1.0f) / (e + 1.0f);
}

// ---------------------------------------------------------------------------
// Phase A (single pass): zero magg slice, per-chunk LDS bucket count ->
// global atomic segment reservation in gcnt -> clustered write into
// fixed-capacity bucket regions. rec = src | et<<17 | (dst&127)<<21
// ---------------------------------------------------------------------------
__global__ __launch_bounds__(1024) void scat_k(const int* __restrict__ src,
                                               const int* __restrict__ dst,
                                               const int* __restrict__ et,
                                               int* __restrict__ gcnt,
                                               int* __restrict__ rec,
                                               float* __restrict__ magg) {
    __shared__ int cnt[NBK];
    const int t = threadIdx.x, ch = blockIdx.x;

    // zero this block's slice of magg (stream-ordered before agg3 reads it)
    {
        const int per = (MAGG_N / 4 + NCH - 1) / NCH;   // float4 units per block
        float4* m4 = (float4*)magg;
        int s0 = ch * per;
        int s1 = s0 + per; if (s1 > MAGG_N / 4) s1 = MAGG_N / 4;
        const float4 z = {0.f, 0.f, 0.f, 0.f};
        for (int k = s0 + t; k < s1; k += 1024) m4[k] = z;
    }

    for (int k = t; k < NBK; k += 1024) cnt[k] = 0;
    __syncthreads();
    int dcache[CHSZ / 1024];
    #pragma unroll
    for (int k = 0; k < CHSZ / 1024; k++) {
        int e = ch * CHSZ + k * 1024 + t;
        dcache[k] = (e < NEDGES) ? dst[e] : -1;
        if (dcache[k] >= 0) atomicAdd(&cnt[dcache[k] >> BSH], 1);
    }
    __syncthreads();
    // reserve this block's sub-segment in each bucket; cnt[b] becomes cursor
    for (int k = t; k < NBK; k += 1024) {
        int c = cnt[k];
        cnt[k] = c ? atomicAdd(&gcnt[k], c) : 0;
    }
    __syncthreads();
    #pragma unroll
    for (int k = 0; k < CHSZ / 1024; k++) {
        int e = ch * CHSZ + k * 1024 + t;
        if (e < NEDGES) {
            int d = dcache[k];
            int b = d >> BSH;
            int pos = atomicAdd(&cnt[b], 1);
            rec[b * BCAP + pos] = src[e] | (et[e] << 17) | ((d & 127) << 21);
        }
    }
}

// ---------------------------------------------------------------------------
// Phase B: in-LDS counting sort of each bucket by dst&127 -> fully dst-sorted
// within the bucket region (enables run compression in agg3). 512 threads.
// ---------------------------------------------------------------------------
__global__ __launch_bounds__(512) void sort2_k(const int* __restrict__ gcnt,
                                               int* __restrict__ rec) {
    __shared__ int buf[BCAP];
    __shared__ int cnt[128];
    __shared__ int basec[128];
    __shared__ int wtot[4];
    const int t = threadIdx.x, b = blockIdx.x;
    const int jb = b * BCAP;
    const int len = gcnt[b];
    if (len <= 0) return;

    if (t < 128) cnt[t] = 0;
    for (int k = t; k < len; k += 512) buf[k] = rec[jb + k];
    __syncthreads();
    for (int k = t; k < len; k += 512) atomicAdd(&cnt[((unsigned)buf[k]) >> 21], 1);
    __syncthreads();
    int v = (t < 128) ? cnt[t] : 0;
    int lane = t & 63, w = t >> 6;
    int s = v;
    #pragma unroll
    for (int d = 1; d < 64; d <<= 1) {
        int u = __shfl_up(s, d, 64);
        if (lane >= d) s += u;
    }
    if (lane == 63 && w < 2) wtot[w] = s;
    __syncthreads();
    if (t < 128) basec[t] = s - v + (w == 1 ? wtot[0] : 0);
    __syncthreads();
    for (int k = t; k < len; k += 512) {
        int r = buf[k];
        int p = atomicAdd(&basec[((unsigned)r) >> 21], 1);
        rec[jb + p] = r;
    }
}

// ---------------------------------------------------------------------------
// Phase C: flat aggregation (round-12 proven body). Block (b,br) covers
// slots [br*512, br*512+512) of bucket b; 16-lane group owns 16 slots.
// Paired pre-issued gathers, register run-compression, ASTR=20 A-layout.
// NOTE: the loop-carried cur/macc register state is load-bearing — it is
// what keeps VGPR>=32 and the 8-float4 gather pipeline in registers
// (removing it -> VGPR 24 -> serialized loads, 2.5x slower; rounds 11/16).
// ---------------------------------------------------------------------------
__global__ __launch_bounds__(512) void agg3_k(const float* __restrict__ feat,
                                              const int* __restrict__ rec,
                                              const int* __restrict__ gcnt,
                                              const float* __restrict__ edge_emb,
                                              float* __restrict__ magg) {
    __shared__ float At2[NTYPE * ATY];   // 20.5 KB
    __shared__ int recs[512];            // 2 KB
    const int t = threadIdx.x;
    const int b  = blockIdx.x / BLKPB;
    const int br = blockIdx.x % BLKPB;
    const int cnt = gcnt[b];
    const int w0 = br << 9;
    if (w0 >= cnt) return;               // uniform: whole block idle

    #pragma unroll
    for (int idx = t; idx < NTYPE * MSG * HID; idx += 512) {
        int ty = idx >> 8, rem = idx & 255, ii = rem >> 4, h = rem & 15;
        At2[ty * ATY + ii * ASTR + h] = edge_emb[idx];
    }
    {
        int ns = BCAP - w0; ns = ns > 512 ? 512 : ns;
        if (t < ns) recs[t] = rec[b * BCAP + w0 + t];
    }
    __syncthreads();

    const int g = t >> 4, i = t & 15;
    const int base = g << 4;
    int vr = cnt - (w0 + base);
    if (vr <= 0) return;
    const int vcnt = vr > 16 ? 16 : vr;

    float macc = 0.0f;
    int cur = -1;
    #pragma unroll 1
    for (int p = 0; p < 16; p += 2) {
        if (p >= vcnt) break;
        const bool has2 = (p + 1) < vcnt;
        int r1 = recs[base + p];
        int r2 = has2 ? recs[base + p + 1] : r1;
        const float4* f1 = (const float4*)(feat + (size_t)(r1 & 0x1FFFF) * HID);
        const float4* f2 = (const float4*)(feat + (size_t)(r2 & 0x1FFFF) * HID);
        float4 Fa0 = f1[0], Fa1 = f1[1], Fa2 = f1[2], Fa3 = f1[3];
        float4 Fb0 = f2[0], Fb1 = f2[1], Fb2 = f2[2], Fb3 = f2[3];
        __builtin_amdgcn_sched_barrier(0);   // keep both gathers issued above

        {
            const float4* pa = (const float4*)(At2 + ((r1 >> 17) & 15) * ATY + i * ASTR);
            float4 A0 = pa[0], A1 = pa[1], A2 = pa[2], A3 = pa[3];
            float m1;
            m1  = A0.x*Fa0.x + A0.y*Fa0.y + A0.z*Fa0.z + A0.w*Fa0.w;
            m1 += A1.x*Fa1.x + A1.y*Fa1.y + A1.z*Fa1.z + A1.w*Fa1.w;
            m1 += A2.x*Fa2.x + A2.y*Fa2.y + A2.z*Fa2.z + A2.w*Fa2.w;
            m1 += A3.x*Fa3.x + A3.y*Fa3.y + A3.z*Fa3.z + A3.w*Fa3.w;
            int d1 = (b << BSH) | (((unsigned)r1) >> 21);
            if (d1 != cur) {
                if (cur >= 0) atomicAdd(&magg[(size_t)cur * MSG + i], macc);
                macc = 0.0f; cur = d1;
            }
            macc += m1;
        }
        if (has2) {
            const float4* pb = (const float4*)(At2 + ((r2 >> 17) & 15) * ATY + i * ASTR);
            float4 B0 = pb[0], B1 = pb[1], B2 = pb[2], B3 = pb[3];
            float m2;
            m2  = B0.x*Fb0.x + B0.y*Fb0.y + B0.z*Fb0.z + B0.w*Fb0.w;
            m2 += B1.x*Fb1.x + B1.y*Fb1.y + B1.z*Fb1.z + B1.w*Fb1.w;
            m2 += B2.x*Fb2.x + B2.y*Fb2.y + B2.z*Fb2.z + B2.w*Fb2.w;
            m2 += B3.x*Fb3.x + B3.y*Fb3.y + B3.z*Fb3.z + B3.w*Fb3.w;
            int d2 = (b << BSH) | (((unsigned)r2) >> 21);
            if (d2 != cur) {
                atomicAdd(&magg[(size_t)cur * MSG + i], macc);
                macc = 0.0f; cur = d2;
            }
            macc += m2;
        }
    }
    atomicAdd(&magg[(size_t)cur * MSG + i], macc);
}

// ---------------------------------------------------------------------------
// Fallback atomic edge kernel (only if ws too small)
// ---------------------------------------------------------------------------
__global__ __launch_bounds__(256) void ggnn_edge(
    const float* __restrict__ feat,
    const int* __restrict__ src,
    const int* __restrict__ dst,
    const int* __restrict__ etype,
    const float* __restrict__ edge_emb,
    float* __restrict__ magg)
{
    __shared__ float At[NTYPE * MSG * HID];
    for (int idx = threadIdx.x; idx < NTYPE * MSG * HID; idx += 256) {
        int ty = idx >> 8, rem = idx & 255, i = rem >> 4, hh = rem & 15;
        At[(ty << 8) | (hh << 4) | i] = edge_emb[idx];
    }
    __syncthreads();
    const long long total = (long long)NEDGES * MSG;
    for (long long w = (long long)blockIdx.x * 256 + threadIdx.x; w < total;
         w += (long long)gridDim.x * 256) {
        const int e = (int)(w >> 4);
        const int i = (int)(w & 15);
        const int s = src[e];
        const int d = dst[e];
        const int ty = etype[e];
        const float4* fp = (const float4*)(feat + (size_t)s * HID);
        const float4 f0 = fp[0], f1 = fp[1], f2 = fp[2], f3 = fp[3];
        const float* a = At + (ty << 8) + i;
        float m;
        m  = a[0*16]*f0.x + a[1*16]*f0.y + a[2*16]*f0.z + a[3*16]*f0.w;
        m += a[4*16]*f1.x + a[5*16]*f1.y + a[6*16]*f1.z + a[7*16]*f1.w;
        m += a[8*16]*f2.x + a[9*16]*f2.y + a[10*16]*f2.z + a[11*16]*f2.w;
        m += a[12*16]*f3.x + a[13*16]*f3.y + a[14*16]*f3.z + a[15*16]*f3.w;
        atomicAdd(magg + (size_t)d * MSG + i, m);
    }
}

// ---------------------------------------------------------------------------
// Node kernel: GRU -> hnew in LDS -> output head with float4 stores.
// ---------------------------------------------------------------------------
__global__ __launch_bounds__(256) void node_k(
    const float* __restrict__ feat,
    const float* __restrict__ magg,
    const float* __restrict__ W_ih,
    const float* __restrict__ W_hh,
    const float* __restrict__ b_ih,
    const float* __restrict__ b_hh,
    const float* __restrict__ W_out,
    const float* __restrict__ b_out,
    float* __restrict__ out)
{
    __shared__ float hn_s[256 * 20];
    const int t = threadIdx.x;
    const int n = blockIdx.x * 256 + t;
    if (n < NNODES) {
        float hv[HID], mv[MSG];
        const float4* hp = (const float4*)(feat + (size_t)n * HID);
        const float4* mp = (const float4*)(magg + (size_t)n * MSG);
        #pragma unroll
        for (int q = 0; q < 4; q++) {
            float4 a = hp[q];
            hv[4*q+0] = a.x; hv[4*q+1] = a.y; hv[4*q+2] = a.z; hv[4*q+3] = a.w;
            float4 c = mp[q];
            mv[4*q+0] = c.x; mv[4*q+1] = c.y; mv[4*q+2] = c.z; mv[4*q+3] = c.w;
        }
        #pragma unroll
        for (int i = 0; i < HID; i++) {
            float xr = b_ih[i], xz = b_ih[16 + i], xn = b_ih[32 + i];
            float hr = b_hh[i], hz = b_hh[16 + i], hn = b_hh[32 + i];
            #pragma unroll
            for (int j = 0; j < HID; j++) {
                xr += W_ih[(i)      * 16 + j] * mv[j];
                xz += W_ih[(16 + i) * 16 + j] * mv[j];
                xn += W_ih[(32 + i) * 16 + j] * mv[j];
                hr += W_hh[(i)      * 16 + j] * hv[j];
                hz += W_hh[(16 + i) * 16 + j] * hv[j];
                hn += W_hh[(32 + i) * 16 + j] * hv[j];
            }
            float r  = sigmoid_f(xr + hr);
            float z  = sigmoid_f(xz + hz);
            float nn = tanh_f(xn + r * hn);
            hn_s[t * 20 + i] = (1.0f - z) * nn + z * hv[i];
        }
    }
    __syncthreads();

    const int w = t >> 6, g = (t >> 4) & 3, li = t & 15;
    float4 w4[4][4];
    #pragma unroll
    for (int rr = 0; rr < 4; rr++)
        #pragma unroll
        for (int qq = 0; qq < 4; qq++)
            w4[rr][qq] = ((const float4*)W_out)[(4 * li + rr) * 4 + qq];
    const float4 bo4 = ((const float4*)b_out)[li];
    const int nb = blockIdx.x * 256;

    #pragma unroll
    for (int it = 0; it < 16; it++) {
        int ln = it * 16 + w * 4 + g;
        int n2 = nb + ln;
        if (n2 < NNODES) {
            const float4* hq = (const float4*)(hn_s + ln * 20);
            float4 h0 = hq[0], h1 = hq[1], h2 = hq[2], h3 = hq[3];
            float4 o;
            o.x = bo4.x + w4[0][0].x*h0.x + w4[0][0].y*h0.y + w4[0][0].z*h0.z + w4[0][0].w*h0.w
                        + w4[0][1].x*h1.x + w4[0][1].y*h1.y + w4[0][1].z*h1.z + w4[0][1].w*h1.w
                        + w4[0][2].x*h2.x + w4[0][2].y*h2.y + w4[0][2].z*h2.z + w4[0][2].w*h2.w
                        + w4[0][3].x*h3.x + w4[0][3].y*h3.y + w4[0][3].z*h3.z + w4[0][3].w*h3.w;
            o.y = bo4.y + w4[1][0].x*h0.x + w4[1][0].y*h0.y + w4[1][0].z*h0.z + w4[1][0].w*h0.w
                        + w4[1][1].x*h1.x + w4[1][1].y*h1.y + w4[1][1].z*h1.z + w4[1][1].w*h1.w
                        + w4[1][2].x*h2.x + w4[1][2].y*h2.y + w4[1][2].z*h2.z + w4[1][2].w*h2.w
                        + w4[1][3].x*h3.x + w4[1][3].y*h3.y + w4[1][3].z*h3.z + w4[1][3].w*h3.w;
            o.z = bo4.z + w4[2][0].x*h0.x + w4[2][0].y*h0.y + w4[2][0].z*h0.z + w4[2][0].w*h0.w
                        + w4[2][1].x*h1.x + w4[2][1].y*h1.y + w4[2][1].z*h1.z + w4[2][1].w*h1.w
                        + w4[2][2].x*h2.x + w4[2][2].y*h2.y + w4[2][2].z*h2.z + w4[2][2].w*h2.w
                        + w4[2][3].x*h3.x + w4[2][3].y*h3.y + w4[2][3].z*h3.z + w4[2][3].w*h3.w;
            o.w = bo4.w + w4[3][0].x*h0.x + w4[3][0].y*h0.y + w4[3][0].z*h0.z + w4[3][0].w*h0.w
                        + w4[3][1].x*h1.x + w4[3][1].y*h1.y + w4[3][1].z*h1.z + w4[3][1].w*h1.w
                        + w4[3][2].x*h2.x + w4[3][2].y*h2.y + w4[3][2].z*h2.z + w4[3][2].w*h2.w
                        + w4[3][3].x*h3.x + w4[3][3].y*h3.y + w4[3][3].z*h3.z + w4[3][3].w*h3.w;
            ((float4*)(out + (size_t)n2 * NCLS))[li] = o;
        }
    }
}

extern "C" void kernel_launch(void* const* d_in, const int* in_sizes, int n_in,
                              void* d_out, int out_size, void* d_ws, size_t ws_size,
                              hipStream_t stream) {
    const float* feat     = (const float*)d_in[0];
    const int*   src      = (const int*)d_in[1];
    const int*   dst      = (const int*)d_in[2];
    const int*   etype    = (const int*)d_in[3];
    const float* edge_emb = (const float*)d_in[4];
    const float* W_ih     = (const float*)d_in[5];
    const float* W_hh     = (const float*)d_in[6];
    const float* b_ih     = (const float*)d_in[7];
    const float* b_hh     = (const float*)d_in[8];
    const float* W_out    = (const float*)d_in[9];
    const float* b_out    = (const float*)d_in[10];
    float* out = (float*)d_out;

    // workspace layout (4-byte elements): ~13.6 MB (proven budget)
    float* magg = (float*)d_ws;                        // NNODES*16
    int*   gcnt = (int*)d_ws + (size_t)MAGG_N;         // 1024 (NBK used)
    int*   rec  = gcnt + 1024;                         // NBK*BCAP
    size_t need = ((size_t)MAGG_N + 1024 + (size_t)NBK * BCAP) * 4;

    if (ws_size >= need) {
        hipMemsetAsync(gcnt, 0, 1024 * sizeof(int), stream);   // tiny
        scat_k  <<<NCH, 1024, 0, stream>>>(src, dst, etype, gcnt, rec, magg);
        sort2_k <<<NBK, 512, 0, stream>>>(gcnt, rec);
        agg3_k  <<<AGG_BLOCKS, 512, 0, stream>>>(feat, rec, gcnt, edge_emb, magg);
    } else {
        hipMemsetAsync(magg, 0, (size_t)MAGG_N * sizeof(float), stream);
        ggnn_edge<<<2560, 256, 0, stream>>>(feat, src, dst, etype, edge_emb, magg);
    }
    node_k<<<(NNODES + 255) / 256, 256, 0, stream>>>(
        feat, magg, W_ih, W_hh, b_ih, b_hh, W_out, b_out, out);
}